// Round 11
// baseline (257.026 us; speedup 1.0000x reference)
//
#include <hip/hip_runtime.h>
#include <math.h>

#define Bsz 2
#define Sq  4096
#define Dm  512
#define Hn  8
#define Eh  64

typedef unsigned short u16;
typedef __attribute__((ext_vector_type(8))) short bf16x8;   // 8 bf16 in 4 VGPRs
typedef __attribute__((ext_vector_type(4))) short bf16x4;   // 4 bf16 in 2 VGPRs
typedef __attribute__((ext_vector_type(4))) float f32x4;
typedef __attribute__((ext_vector_type(4))) unsigned short u16x4;

// K pre-scale: 1/sqrt(64) * log2(e), folded into k so softmax is a bare exp2.
#define KSCALE 0.18033688011112042f

// 16x16x16 bf16 MFMA (K=16, A/B = 4 bf16 per lane, k = quad*4+j).
// Guarded so the HOST pass (which lacks the builtin) compiles a dummy body.
__device__ __forceinline__ f32x4 mfma_16x16x16(bf16x4 a, bf16x4 b, f32x4 c) {
#if defined(__HIP_DEVICE_COMPILE__)
#if __has_builtin(__builtin_amdgcn_mfma_f32_16x16x16bf16_1k)
    return __builtin_amdgcn_mfma_f32_16x16x16bf16_1k(a, b, c, 0, 0, 0);
#else
    f32x4 d;
    asm volatile("v_mfma_f32_16x16x16_bf16 %0, %1, %2, %3"
                 : "=v"(d) : "v"(a), "v"(b), "v"(c));
    return d;
#endif
#else
    (void)a; (void)b;
    return c;
#endif
}

__device__ __forceinline__ u16 f2bf(float f) {
    unsigned int u = __float_as_uint(f);
    u += 0x7FFFu + ((u >> 16) & 1u);          // round-to-nearest-even
    return (u16)(u >> 16);
}

__device__ __forceinline__ float fast_exp2(float x) {
#if defined(__HIP_DEVICE_COMPILE__) && __has_builtin(__builtin_amdgcn_exp2f)
    return __builtin_amdgcn_exp2f(x);
#else
    return exp2f(x);
#endif
}

// async global->LDS, 16B per lane. LDS dest = wave-uniform base + lane*16.
__device__ __forceinline__ void async16(const u16* g, u16* l) {
    __builtin_amdgcn_global_load_lds(
        (const __attribute__((address_space(1))) void*)g,
        (__attribute__((address_space(3))) void*)l, 16, 0, 0);
}

// ---------------------------------------------------------------------------
// bf16 MFMA GEMM core, LDS DOUBLE-BUFFERED (r10-validated mechanism):
// one barrier per K-tile; tile kt+1's global_load_lds issued right after,
// landing in the other buffer while tile kt computes.
// C[128 x TN] += A[128,512] * WT[TN,512]^T, K=Dm=512.
// Global-side XOR chunk swizzle (LDS slot s holds global chunk s^(row&7))
// keeps frag b128 reads conflict-free. 4 waves as 2(M)x2(N).
// Ast = 2 x 128*64 u16, Bst = 2 x TN*64 u16.
// ---------------------------------------------------------------------------
template<int TN, int NT>
__device__ __forceinline__ void gemm_core(
    const u16* __restrict__ A, const u16* __restrict__ WT,
    int m0, int n0, u16* Ast, u16* Bst, f32x4 (&acc)[4][NT])
{
    const int tid  = threadIdx.x;
    const int lane = tid & 63, wid = tid >> 6;
    const int l15  = lane & 15, quad = lane >> 4;
    const int wm = wid >> 1, wn = wid & 1;

    // staging geometry (wave-uniform LDS bases, lane-linear dest)
    int arow[4], acol[4];
#pragma unroll
    for (int j = 0; j < 4; ++j) {
        int ci = wid * 256 + j * 64 + lane;
        arow[j] = ci >> 3;
        acol[j] = (ci & 7) ^ (arow[j] & 7);
    }
    int brow[TN / 32], bcol[TN / 32];
#pragma unroll
    for (int j = 0; j < TN / 32; ++j) {
        int ci = wid * (TN * 2) + j * 64 + lane;
        brow[j] = ci >> 3;
        bcol[j] = (ci & 7) ^ (brow[j] & 7);
    }

    // issue tile 0 into buffer 0
#pragma unroll
    for (int j = 0; j < 4; ++j)
        async16(&A[(size_t)(m0 + arow[j]) * Dm + acol[j] * 8],
                &Ast[(wid * 256 + j * 64) * 8]);
#pragma unroll
    for (int j = 0; j < TN / 32; ++j)
        async16(&WT[(size_t)(n0 + brow[j]) * Dm + bcol[j] * 8],
                &Bst[(wid * (TN * 2) + j * 64) * 8]);

    for (int kt = 0; kt < Dm / 64; ++kt) {
        const int cur = kt & 1;
        __syncthreads();   // drains tile kt's async loads; frees other buffer

        if (kt + 1 < Dm / 64) {
            const int k1 = (kt + 1) * 64;
            const int nx = cur ^ 1;
#pragma unroll
            for (int j = 0; j < 4; ++j)
                async16(&A[(size_t)(m0 + arow[j]) * Dm + k1 + acol[j] * 8],
                        &Ast[nx * 128 * 64 + (wid * 256 + j * 64) * 8]);
#pragma unroll
            for (int j = 0; j < TN / 32; ++j)
                async16(&WT[(size_t)(n0 + brow[j]) * Dm + k1 + bcol[j] * 8],
                        &Bst[nx * TN * 64 + (wid * (TN * 2) + j * 64) * 8]);
        }

        const u16* Acur = Ast + cur * 128 * 64;
        const u16* Bcur = Bst + cur * TN * 64;
#pragma unroll
        for (int ks = 0; ks < 2; ++ks) {
            bf16x8 af[4], bfr[NT];
#pragma unroll
            for (int mt = 0; mt < 4; ++mt) {
                int r = wm * 64 + mt * 16 + l15;
                af[mt] = *(const bf16x8*)&Acur[(r * 8 + ((ks * 4 + quad) ^ (r & 7))) * 8];
            }
#pragma unroll
            for (int nt = 0; nt < NT; ++nt) {
                int n = wn * (TN / 2) + nt * 16 + l15;
                bfr[nt] = *(const bf16x8*)&Bcur[(n * 8 + ((ks * 4 + quad) ^ (n & 7))) * 8];
            }
#pragma unroll
            for (int mt = 0; mt < 4; ++mt)
#pragma unroll
                for (int nt = 0; nt < NT; ++nt)
                    acc[mt][nt] = __builtin_amdgcn_mfma_f32_16x16x32_bf16(
                        af[mt], bfr[nt], acc[mt][nt], 0, 0, 0);
        }
    }
}

// ---------------------------------------------------------------------------
// prep: seg0 x->bf16; seg1-3 wq/wk/wv transpose; seg4-6 wo/w1/w2 transpose;
// seg7 bo reduce.
// ---------------------------------------------------------------------------
__global__ __launch_bounds__(256) void prep_kernel(
    const float* __restrict__ x,
    const float* __restrict__ wq, const float* __restrict__ wk,
    const float* __restrict__ wv, const float* __restrict__ wo,
    const float* __restrict__ w1, const float* __restrict__ w2,
    const float* __restrict__ bo,
    u16* __restrict__ xb, u16* __restrict__ wqkvT, u16* __restrict__ woT,
    u16* __restrict__ w1T, u16* __restrict__ w2T, float* __restrict__ bo_s)
{
    const int seg = blockIdx.y, bx = blockIdx.x, tid = threadIdx.x;
    if (seg == 0) {
        const float4* xi = (const float4*)x;
        for (int i = bx * 256 + tid; i < (Bsz * Sq * Dm) / 4; i += 64 * 256) {
            float4 v = xi[i];
            u16x4 o = {f2bf(v.x), f2bf(v.y), f2bf(v.z), f2bf(v.w)};
            *(u16x4*)&xb[(size_t)i * 4] = o;
        }
        return;
    }
    if (seg == 7) {
        int d = bx * 256 + tid;
        if (d < Dm) {
            float s = 0.0f;
#pragma unroll
            for (int h = 0; h < Hn; ++h) s += bo[h * Dm + d];
            bo_s[d] = s;
        }
        return;
    }
    __shared__ float t[64][65];
    const float* src; u16* dst; int ld_in;
    if (seg <= 3) {
        const float* w = (seg == 1) ? wq : (seg == 2) ? wk : wv;
        int head = bx >> 3, kt = bx & 7;
        src = w + (size_t)head * Dm * Eh + (size_t)kt * 64 * 64;
        ld_in = 64;
        dst = wqkvT + ((size_t)((seg - 1) * 8 + head) * 64) * 512 + kt * 64;
    } else {
        const float* w = (seg == 4) ? wo : (seg == 5) ? w1 : w2;
        u16* dT = (seg == 4) ? woT : (seg == 5) ? w1T : w2T;
        int tr = bx >> 3, tc = bx & 7;
        src = w + (size_t)(tr * 64) * 512 + tc * 64;
        ld_in = 512;
        dst = dT + (size_t)(tc * 64) * 512 + tr * 64;
    }
#pragma unroll
    for (int it = 0; it < 16; ++it) {
        int idx = it * 256 + tid;
        int r = idx >> 6, c = idx & 63;
        t[r][c] = src[(size_t)r * ld_in + c];
    }
    __syncthreads();
#pragma unroll
    for (int it = 0; it < 4; ++it) {
        int idx = it * 256 + tid;
        int oc = idx >> 4, og = idx & 15;
        u16x4 o;
#pragma unroll
        for (int j = 0; j < 4; ++j) o[j] = f2bf(t[og * 4 + j][oc]);
        *(u16x4*)&dst[(size_t)oc * 512 + og * 4] = o;
    }
}

// ---------------------------------------------------------------------------
// QKV: grid (64, 24). Tile 128x64. q -> [bh][s][e]; k -> [bh][s][e] scaled
// by KSCALE (folded softmax scale + log2e); v -> transposed [bh][e][s].
// ---------------------------------------------------------------------------
__global__ __launch_bounds__(256, 2) void qkv_gemm(
    const u16* __restrict__ xb, const u16* __restrict__ wqkvT,
    const float* __restrict__ bq, const float* __restrict__ bk,
    const float* __restrict__ bv,
    u16* __restrict__ qb, u16* __restrict__ kb, u16* __restrict__ vbT)
{
    __shared__ __align__(16) u16 Ast[2 * 128 * 64];
    __shared__ __align__(16) u16 Bst[2 * 64 * 64];
    const int proj = blockIdx.y >> 3, h = blockIdx.y & 7;
    const u16* WT = wqkvT + (size_t)blockIdx.y * 64 * 512;

    f32x4 acc[4][2];
#pragma unroll
    for (int i = 0; i < 4; ++i)
#pragma unroll
        for (int j = 0; j < 2; ++j) acc[i][j] = (f32x4)0.0f;

    gemm_core<64, 2>(xb, WT, blockIdx.x * 128, 0, Ast, Bst, acc);

    const int tid = threadIdx.x;
    const int lane = tid & 63, wid = tid >> 6;
    const int l15 = lane & 15, quad = lane >> 4;
    const int wm = wid >> 1, wn = wid & 1;
    const float* bias = (proj == 0) ? bq : (proj == 1) ? bk : bv;

    const int mbase = blockIdx.x * 128 + wm * 64;
    const int b = mbase >> 12;
    const int sbase = (mbase & (Sq - 1));
    const int bh = b * Hn + h;

#pragma unroll
    for (int mt = 0; mt < 4; ++mt)
#pragma unroll
        for (int nt = 0; nt < 2; ++nt) {
            int e = wn * 32 + nt * 16 + l15;
            float bval = bias[h * Eh + e];
            int s = sbase + mt * 16 + quad * 4;
            if (proj == 2) {
                u16x4 o;
#pragma unroll
                for (int r = 0; r < 4; ++r) o[r] = f2bf(acc[mt][nt][r] + bval);
                *(u16x4*)&vbT[((size_t)bh * Eh + e) * Sq + s] = o;
            } else if (proj == 1) {
                for (int r = 0; r < 4; ++r)
                    kb[((size_t)bh * Sq + s + r) * Eh + e] =
                        f2bf((acc[mt][nt][r] + bval) * KSCALE);
            } else {
                for (int r = 0; r < 4; ++r)
                    qb[((size_t)bh * Sq + s + r) * Eh + e] = f2bf(acc[mt][nt][r] + bval);
            }
        }
}

// ---------------------------------------------------------------------------
// bf16 MFMA flash attention v10 (unchanged from round 10 — matched
// prediction: 105 us, MfmaUtil 41%, WRITE 8 MB): transposed-score core,
// register P, LDS double-buffer via global_load_lds, one barrier/iter.
// Q-tile 128, grid (32,16), 2 blk/CU.
// ---------------------------------------------------------------------------
__global__ __launch_bounds__(256, 2) void attn_kernel(
    const u16* __restrict__ qb, const u16* __restrict__ kb,
    const u16* __restrict__ vbT, u16* __restrict__ ctxb)
{
    __shared__ __align__(16) u16 kst[2][64 * 64];   // [t][d] chunks, swizzled
    __shared__ __align__(16) u16 vst[2][64 * 64];   // [e][t] chunks, swizzled

    const int tid  = threadIdx.x;
    const int lane = tid & 63, wid = tid >> 6;
    const int l15  = lane & 15, quad = lane >> 4;
    const int bh = blockIdx.y;
    const int q0 = blockIdx.x * 128;
    const int b = bh >> 3, h = bh & 7;

    const u16* qg = qb + (size_t)bh * Sq * Eh;
    const u16* kg = kb + (size_t)bh * Sq * Eh;
    const u16* vg = vbT + (size_t)bh * Eh * Sq;

    int srow[2], scol[2];
#pragma unroll
    for (int j = 0; j < 2; ++j) {
        int ci = wid * 128 + j * 64 + lane;
        srow[j] = ci >> 3;
        scol[j] = (ci & 7) ^ (srow[j] & 7);
    }

    bf16x8 qf[2][2];
#pragma unroll
    for (int qt = 0; qt < 2; ++qt)
#pragma unroll
        for (int ks = 0; ks < 2; ++ks)
            qf[qt][ks] = *(const bf16x8*)&qg[(size_t)(q0 + wid * 32 + qt * 16 + l15) * Eh + ks * 32 + quad * 8];

    f32x4 O[4][2];
    float lp[2];
#pragma unroll
    for (int et = 0; et < 4; ++et)
#pragma unroll
        for (int qt = 0; qt < 2; ++qt) O[et][qt] = (f32x4)0.0f;
    lp[0] = lp[1] = 0.0f;

#pragma unroll
    for (int j = 0; j < 2; ++j) {
        async16(&kg[(size_t)srow[j] * Eh + scol[j] * 8],
                &kst[0][(wid * 128 + j * 64) * 8]);
        async16(&vg[(size_t)srow[j] * Sq + scol[j] * 8],
                &vst[0][(wid * 128 + j * 64) * 8]);
    }

    for (int kt = 0; kt < Sq / 64; ++kt) {
        const int cur = kt & 1;
        __syncthreads();

        if (kt < Sq / 64 - 1) {
            const int t1 = (kt + 1) * 64;
#pragma unroll
            for (int j = 0; j < 2; ++j) {
                async16(&kg[(size_t)(t1 + srow[j]) * Eh + scol[j] * 8],
                        &kst[cur ^ 1][(wid * 128 + j * 64) * 8]);
                async16(&vg[(size_t)srow[j] * Sq + t1 + scol[j] * 8],
                        &vst[cur ^ 1][(wid * 128 + j * 64) * 8]);
            }
        }

        const u16* kcur = kst[cur];
        const u16* vcur = vst[cur];

        f32x4 S[4][2];
#pragma unroll
        for (int tt = 0; tt < 4; ++tt)
#pragma unroll
            for (int qt = 0; qt < 2; ++qt) S[tt][qt] = (f32x4)0.0f;
#pragma unroll
        for (int ks = 0; ks < 2; ++ks)
#pragma unroll
            for (int tt = 0; tt < 4; ++tt) {
                int t = tt * 16 + l15;
                bf16x8 kf = *(const bf16x8*)&kcur[t * 64 + ((ks * 4 + quad) ^ (t & 7)) * 8];
                S[tt][0] = __builtin_amdgcn_mfma_f32_16x16x32_bf16(kf, qf[0][ks], S[tt][0], 0, 0, 0);
                S[tt][1] = __builtin_amdgcn_mfma_f32_16x16x32_bf16(kf, qf[1][ks], S[tt][1], 0, 0, 0);
            }

        bf16x4 pf[4][2];
#pragma unroll
        for (int tt = 0; tt < 4; ++tt)
#pragma unroll
            for (int qt = 0; qt < 2; ++qt)
#pragma unroll
                for (int r = 0; r < 4; ++r) {
                    float p = fast_exp2(S[tt][qt][r]);
                    lp[qt] += p;
                    pf[tt][qt][r] = (short)(__float_as_uint(p) >> 16);
                }

#pragma unroll
        for (int et = 0; et < 4; ++et) {
            int e = et * 16 + l15;
            bf16x4 vf[4];
#pragma unroll
            for (int tt = 0; tt < 4; ++tt) {
                int chunk = (tt * 2 + (quad >> 1)) ^ (e & 7);
                vf[tt] = *(const bf16x4*)&vcur[e * 64 + chunk * 8 + (quad & 1) * 4];
            }
#pragma unroll
            for (int qt = 0; qt < 2; ++qt)
#pragma unroll
                for (int tt = 0; tt < 4; ++tt)
                    O[et][qt] = mfma_16x16x16(vf[tt], pf[tt][qt], O[et][qt]);
        }
    }

#pragma unroll
    for (int qt = 0; qt < 2; ++qt) {
        float v = lp[qt];
        v += __shfl_xor(v, 16, 64);
        v += __shfl_xor(v, 32, 64);
        lp[qt] = v;
    }

#pragma unroll
    for (int qt = 0; qt < 2; ++qt) {
        const int qglob = q0 + wid * 32 + qt * 16 + l15;
        const float rl = 1.0f / lp[qt];
        u16* crow = ctxb + ((size_t)(b * Sq + qglob) * Hn + h) * Eh;
#pragma unroll
        for (int et = 0; et < 4; ++et) {
            u16x4 o;
#pragma unroll
            for (int r = 0; r < 4; ++r) o[r] = f2bf(O[et][qt][r] * rl);
            *(u16x4*)&crow[et * 16 + quad * 4] = o;
        }
    }
}

// ---------------------------------------------------------------------------
// Flat GEMM [8192,512] x WT[512,512], tile 128x64 (512 blocks, 2/CU).
// MODE 0: bf16 out; 1: bf16 out + relu; 2: fp32 out.
// ---------------------------------------------------------------------------
template<int MODE>
__global__ __launch_bounds__(256, 2) void gemmMN(
    const u16* __restrict__ A, const u16* __restrict__ WT,
    const float* __restrict__ bias, void* __restrict__ Cout)
{
    __shared__ __align__(16) u16 Ast[2 * 128 * 64];
    __shared__ __align__(16) u16 Bst[2 * 64 * 64];

    f32x4 acc[4][2];
#pragma unroll
    for (int i = 0; i < 4; ++i)
#pragma unroll
        for (int j = 0; j < 2; ++j) acc[i][j] = (f32x4)0.0f;

    gemm_core<64, 2>(A, WT, blockIdx.x * 128, blockIdx.y * 64, Ast, Bst, acc);

    const int tid = threadIdx.x;
    const int lane = tid & 63, wid = tid >> 6;
    const int l15 = lane & 15, quad = lane >> 4;
    const int m0 = blockIdx.x * 128 + (wid >> 1) * 64;
    const int n0 = blockIdx.y * 64 + (wid & 1) * 32;

#pragma unroll
    for (int mt = 0; mt < 4; ++mt)
#pragma unroll
        for (int nt = 0; nt < 2; ++nt) {
            int col = n0 + nt * 16 + l15;
            float bval = bias[col];
#pragma unroll
            for (int r = 0; r < 4; ++r) {
                int row = m0 + mt * 16 + quad * 4 + r;
                float v = acc[mt][nt][r] + bval;
                if (MODE == 1) v = fmaxf(v, 0.0f);
                if (MODE == 2) ((float*)Cout)[(size_t)row * Dm + col] = v;
                else           ((u16*)Cout)[(size_t)row * Dm + col] = f2bf(v);
            }
        }
}

extern "C" void kernel_launch(void* const* d_in, const int* in_sizes, int n_in,
                              void* d_out, int out_size, void* d_ws, size_t ws_size,
                              hipStream_t stream)
{
    const float* x  = (const float*)d_in[0];
    const float* wq = (const float*)d_in[1];
    const float* bq = (const float*)d_in[2];
    const float* wk = (const float*)d_in[3];
    const float* bk = (const float*)d_in[4];
    const float* wv = (const float*)d_in[5];
    const float* bv = (const float*)d_in[6];
    const float* wo = (const float*)d_in[7];
    const float* bo = (const float*)d_in[8];
    const float* w1 = (const float*)d_in[9];
    const float* b1 = (const float*)d_in[10];
    const float* w2 = (const float*)d_in[11];
    const float* b2 = (const float*)d_in[12];
    float* out = (float*)d_out;
    char* wsb = (char*)d_ws;

    const size_t MB = 1u << 20;
    u16*   xb    = (u16*)(wsb + 0);        // 8 MB  bf16 [B*S, D]
    u16*   qb    = (u16*)(wsb + 8 * MB);   // 8 MB  [bh][s][e]
    u16*   kb    = (u16*)(wsb + 16 * MB);  // 8 MB  [bh][s][e] (pre-scaled)
    u16*   vbT   = (u16*)(wsb + 24 * MB);  // 8 MB  [bh][e][s]
    u16*   ctxb  = (u16*)(wsb + 32 * MB);  // 8 MB  [b][s][h][e]
    u16*   ybuf  = (u16*)(wsb + 40 * MB);  // 8 MB
    u16*   h1    = (u16*)(wsb + 48 * MB);  // 8 MB
    u16*   wqkvT = (u16*)(wsb + 56 * MB);  // 1.5 MB
    u16*   woT   = (u16*)(wsb + 58 * MB);  // 0.5 MB
    u16*   w1T   = (u16*)(wsb + 59 * MB);  // 0.5 MB
    u16*   w2T   = (u16*)(wsb + 60 * MB);  // 0.5 MB
    float* bo_s  = (float*)(wsb + 61 * MB);

    prep_kernel<<<dim3(64, 8), 256, 0, stream>>>(
        x, wq, wk, wv, wo, w1, w2, bo, xb, wqkvT, woT, w1T, w2T, bo_s);
    qkv_gemm<<<dim3(Sq * Bsz / 128, 24), 256, 0, stream>>>(
        xb, wqkvT, bq, bk, bv, qb, kb, vbT);
    attn_kernel<<<dim3(Sq / 128, Bsz * Hn), 256, 0, stream>>>(qb, kb, vbT, ctxb);
    gemmMN<0><<<dim3(Bsz * Sq / 128, Dm / 64), 256, 0, stream>>>(ctxb, woT, bo_s, ybuf);
    gemmMN<1><<<dim3(Bsz * Sq / 128, Dm / 64), 256, 0, stream>>>(ybuf, w1T, b1, h1);
    gemmMN<2><<<dim3(Bsz * Sq / 128, Dm / 64), 256, 0, stream>>>(h1, w2T, b2, out);
}

// Round 12
// 241.977 us; speedup vs baseline: 1.0622x; 1.0622x over previous
//
#include <hip/hip_runtime.h>
#include <math.h>

#define Bsz 2
#define Sq  4096
#define Dm  512
#define Hn  8
#define Eh  64

typedef unsigned short u16;
typedef __attribute__((ext_vector_type(8))) short bf16x8;   // 8 bf16 in 4 VGPRs
typedef __attribute__((ext_vector_type(4))) short bf16x4;   // 4 bf16 in 2 VGPRs
typedef __attribute__((ext_vector_type(4))) float f32x4;
typedef __attribute__((ext_vector_type(4))) unsigned short u16x4;

// K pre-scale: 1/sqrt(64) * log2(e), folded into k so softmax is a bare exp2.
#define KSCALE 0.18033688011112042f

// 16x16x16 bf16 MFMA (K=16, A/B = 4 bf16 per lane, k = quad*4+j).
// Guarded so the HOST pass (which lacks the builtin) compiles a dummy body.
__device__ __forceinline__ f32x4 mfma_16x16x16(bf16x4 a, bf16x4 b, f32x4 c) {
#if defined(__HIP_DEVICE_COMPILE__)
#if __has_builtin(__builtin_amdgcn_mfma_f32_16x16x16bf16_1k)
    return __builtin_amdgcn_mfma_f32_16x16x16bf16_1k(a, b, c, 0, 0, 0);
#else
    f32x4 d;
    asm volatile("v_mfma_f32_16x16x16_bf16 %0, %1, %2, %3"
                 : "=v"(d) : "v"(a), "v"(b), "v"(c));
    return d;
#endif
#else
    (void)a; (void)b;
    return c;
#endif
}

__device__ __forceinline__ u16 f2bf(float f) {
    unsigned int u = __float_as_uint(f);
    u += 0x7FFFu + ((u >> 16) & 1u);          // round-to-nearest-even
    return (u16)(u >> 16);
}

__device__ __forceinline__ float fast_exp2(float x) {
#if defined(__HIP_DEVICE_COMPILE__) && __has_builtin(__builtin_amdgcn_exp2f)
    return __builtin_amdgcn_exp2f(x);
#else
    return exp2f(x);
#endif
}

// async global->LDS, 16B per lane. LDS dest = wave-uniform base + lane*16.
__device__ __forceinline__ void async16(const u16* g, u16* l) {
    __builtin_amdgcn_global_load_lds(
        (const __attribute__((address_space(1))) void*)g,
        (__attribute__((address_space(3))) void*)l, 16, 0, 0);
}

// ---------------------------------------------------------------------------
// bf16 MFMA GEMM core (r10 single-buffered version — r11's double-buffer was
// neutral for these ramp-dominated small kernels, reverted).
// C[128 x TN] += A[128,512] * WT[TN,512]^T, K=Dm=512.
// Global-side XOR chunk swizzle; 4 waves as 2(M)x2(N).
// ---------------------------------------------------------------------------
template<int TN, int NT>
__device__ __forceinline__ void gemm_core(
    const u16* __restrict__ A, const u16* __restrict__ WT,
    int m0, int n0, u16* Ast, u16* Bst, f32x4 (&acc)[4][NT])
{
    const int tid  = threadIdx.x;
    const int lane = tid & 63, wid = tid >> 6;
    const int l15  = lane & 15, quad = lane >> 4;
    const int wm = wid >> 1, wn = wid & 1;

    for (int kt = 0; kt < Dm / 64; ++kt) {
        const int k0 = kt * 64;
        __syncthreads();
#pragma unroll
        for (int j = 0; j < 4; ++j) {
            int ci = wid * 256 + j * 64 + lane;
            int row = ci >> 3, c = (ci & 7) ^ (row & 7);
            async16(&A[(size_t)(m0 + row) * Dm + k0 + c * 8],
                    &Ast[(size_t)(wid * 256 + j * 64) * 8]);
        }
#pragma unroll
        for (int j = 0; j < TN / 32; ++j) {
            int ci = wid * (TN * 2) + j * 64 + lane;
            int row = ci >> 3, c = (ci & 7) ^ (row & 7);
            async16(&WT[(size_t)(n0 + row) * Dm + k0 + c * 8],
                    &Bst[(size_t)(wid * (TN * 2) + j * 64) * 8]);
        }
        __syncthreads();
#pragma unroll
        for (int ks = 0; ks < 2; ++ks) {
            bf16x8 af[4], bfr[NT];
#pragma unroll
            for (int mt = 0; mt < 4; ++mt) {
                int r = wm * 64 + mt * 16 + l15;
                af[mt] = *(const bf16x8*)&Ast[(r * 8 + ((ks * 4 + quad) ^ (r & 7))) * 8];
            }
#pragma unroll
            for (int nt = 0; nt < NT; ++nt) {
                int n = wn * (TN / 2) + nt * 16 + l15;
                bfr[nt] = *(const bf16x8*)&Bst[(n * 8 + ((ks * 4 + quad) ^ (n & 7))) * 8];
            }
#pragma unroll
            for (int mt = 0; mt < 4; ++mt)
#pragma unroll
                for (int nt = 0; nt < NT; ++nt)
                    acc[mt][nt] = __builtin_amdgcn_mfma_f32_16x16x32_bf16(
                        af[mt], bfr[nt], acc[mt][nt], 0, 0, 0);
        }
    }
}

// ---------------------------------------------------------------------------
// prep: seg0 x->bf16; seg1-3 wq/wk/wv transpose; seg4-6 wo/w1/w2 transpose;
// seg7 bo reduce.
// ---------------------------------------------------------------------------
__global__ __launch_bounds__(256) void prep_kernel(
    const float* __restrict__ x,
    const float* __restrict__ wq, const float* __restrict__ wk,
    const float* __restrict__ wv, const float* __restrict__ wo,
    const float* __restrict__ w1, const float* __restrict__ w2,
    const float* __restrict__ bo,
    u16* __restrict__ xb, u16* __restrict__ wqkvT, u16* __restrict__ woT,
    u16* __restrict__ w1T, u16* __restrict__ w2T, float* __restrict__ bo_s)
{
    const int seg = blockIdx.y, bx = blockIdx.x, tid = threadIdx.x;
    if (seg == 0) {
        const float4* xi = (const float4*)x;
        for (int i = bx * 256 + tid; i < (Bsz * Sq * Dm) / 4; i += 64 * 256) {
            float4 v = xi[i];
            u16x4 o = {f2bf(v.x), f2bf(v.y), f2bf(v.z), f2bf(v.w)};
            *(u16x4*)&xb[(size_t)i * 4] = o;
        }
        return;
    }
    if (seg == 7) {
        int d = bx * 256 + tid;
        if (d < Dm) {
            float s = 0.0f;
#pragma unroll
            for (int h = 0; h < Hn; ++h) s += bo[h * Dm + d];
            bo_s[d] = s;
        }
        return;
    }
    __shared__ float t[64][65];
    const float* src; u16* dst; int ld_in;
    if (seg <= 3) {
        const float* w = (seg == 1) ? wq : (seg == 2) ? wk : wv;
        int head = bx >> 3, kt = bx & 7;
        src = w + (size_t)head * Dm * Eh + (size_t)kt * 64 * 64;
        ld_in = 64;
        dst = wqkvT + ((size_t)((seg - 1) * 8 + head) * 64) * 512 + kt * 64;
    } else {
        const float* w = (seg == 4) ? wo : (seg == 5) ? w1 : w2;
        u16* dT = (seg == 4) ? woT : (seg == 5) ? w1T : w2T;
        int tr = bx >> 3, tc = bx & 7;
        src = w + (size_t)(tr * 64) * 512 + tc * 64;
        ld_in = 512;
        dst = dT + (size_t)(tc * 64) * 512 + tr * 64;
    }
#pragma unroll
    for (int it = 0; it < 16; ++it) {
        int idx = it * 256 + tid;
        int r = idx >> 6, c = idx & 63;
        t[r][c] = src[(size_t)r * ld_in + c];
    }
    __syncthreads();
#pragma unroll
    for (int it = 0; it < 4; ++it) {
        int idx = it * 256 + tid;
        int oc = idx >> 4, og = idx & 15;
        u16x4 o;
#pragma unroll
        for (int j = 0; j < 4; ++j) o[j] = f2bf(t[og * 4 + j][oc]);
        *(u16x4*)&dst[(size_t)oc * 512 + og * 4] = o;
    }
}

// ---------------------------------------------------------------------------
// QKV: grid (64, 24). Tile 128x64. q -> [bh][s][e]; k -> [bh][s][e] scaled
// by KSCALE (folded softmax scale + log2e); v -> transposed [bh][e][s].
// ---------------------------------------------------------------------------
__global__ __launch_bounds__(256, 2) void qkv_gemm(
    const u16* __restrict__ xb, const u16* __restrict__ wqkvT,
    const float* __restrict__ bq, const float* __restrict__ bk,
    const float* __restrict__ bv,
    u16* __restrict__ qb, u16* __restrict__ kb, u16* __restrict__ vbT)
{
    __shared__ __align__(16) u16 Ast[128 * 64];
    __shared__ __align__(16) u16 Bst[64 * 64];
    const int proj = blockIdx.y >> 3, h = blockIdx.y & 7;
    const u16* WT = wqkvT + (size_t)blockIdx.y * 64 * 512;

    f32x4 acc[4][2];
#pragma unroll
    for (int i = 0; i < 4; ++i)
#pragma unroll
        for (int j = 0; j < 2; ++j) acc[i][j] = (f32x4)0.0f;

    gemm_core<64, 2>(xb, WT, blockIdx.x * 128, 0, Ast, Bst, acc);

    const int tid = threadIdx.x;
    const int lane = tid & 63, wid = tid >> 6;
    const int l15 = lane & 15, quad = lane >> 4;
    const int wm = wid >> 1, wn = wid & 1;
    const float* bias = (proj == 0) ? bq : (proj == 1) ? bk : bv;

    const int mbase = blockIdx.x * 128 + wm * 64;
    const int b = mbase >> 12;
    const int sbase = (mbase & (Sq - 1));
    const int bh = b * Hn + h;

#pragma unroll
    for (int mt = 0; mt < 4; ++mt)
#pragma unroll
        for (int nt = 0; nt < 2; ++nt) {
            int e = wn * 32 + nt * 16 + l15;
            float bval = bias[h * Eh + e];
            int s = sbase + mt * 16 + quad * 4;
            if (proj == 2) {
                u16x4 o;
#pragma unroll
                for (int r = 0; r < 4; ++r) o[r] = f2bf(acc[mt][nt][r] + bval);
                *(u16x4*)&vbT[((size_t)bh * Eh + e) * Sq + s] = o;
            } else if (proj == 1) {
                for (int r = 0; r < 4; ++r)
                    kb[((size_t)bh * Sq + s + r) * Eh + e] =
                        f2bf((acc[mt][nt][r] + bval) * KSCALE);
            } else {
                for (int r = 0; r < 4; ++r)
                    qb[((size_t)bh * Sq + s + r) * Eh + e] = f2bf(acc[mt][nt][r] + bval);
            }
        }
}

// ---------------------------------------------------------------------------
// bf16 MFMA flash attention v12 = r10 core + K-TILE 128 (32 iterations
// instead of 64): per-iteration barrier/drain overhead (~2700 idle cyc of
// the 4012-cyc iteration, per r10 counters) is paid half as often while
// pipe work per iteration doubles. LDS 64 KB (2 blocks/CU unchanged —
// grid 512 is the occupancy cap). S computed in two tt-halves to bound
// register pressure (spill watch: VGPR drop + WRITE_SIZE bloat = r9 sig).
// ---------------------------------------------------------------------------
__global__ __launch_bounds__(256, 2) void attn_kernel(
    const u16* __restrict__ qb, const u16* __restrict__ kb,
    const u16* __restrict__ vbT, u16* __restrict__ ctxb)
{
    __shared__ __align__(16) u16 kst[2][128 * 64];  // [t][d] chunks, swizzled
    __shared__ __align__(16) u16 vst[2][64 * 128];  // [e][t] chunks, swizzled

    const int tid  = threadIdx.x;
    const int lane = tid & 63, wid = tid >> 6;
    const int l15  = lane & 15, quad = lane >> 4;
    const int bh = blockIdx.y;
    const int q0 = blockIdx.x * 128;
    const int b = bh >> 3, h = bh & 7;

    const u16* qg = qb + (size_t)bh * Sq * Eh;
    const u16* kg = kb + (size_t)bh * Sq * Eh;
    const u16* vg = vbT + (size_t)bh * Eh * Sq;

    // staging geometry: 1024 chunks per tensor, 4 async16/wave/tensor.
    // K tile [t 0..127][d 0..63]: row=ci>>3, col=ci&7, XOR row&7.
    // V tile [e 0..63][t 0..127]: row=ci>>4, col=ci&15, XOR low-3 bits.
    int krow[4], kcol[4], vrow[4], vcol[4];
#pragma unroll
    for (int j = 0; j < 4; ++j) {
        int ci = wid * 256 + j * 64 + lane;
        krow[j] = ci >> 3;
        kcol[j] = (ci & 7) ^ (krow[j] & 7);
        vrow[j] = ci >> 4;
        int vc  = ci & 15;
        vcol[j] = (vc & 8) | ((vc & 7) ^ (vrow[j] & 7));
    }

    // Q B-frags (B[n=q][k=d]) in registers for the whole kernel
    bf16x8 qf[2][2];
#pragma unroll
    for (int qt = 0; qt < 2; ++qt)
#pragma unroll
        for (int ks = 0; ks < 2; ++ks)
            qf[qt][ks] = *(const bf16x8*)&qg[(size_t)(q0 + wid * 32 + qt * 16 + l15) * Eh + ks * 32 + quad * 8];

    f32x4 O[4][2];      // O^T[et][qt]
    float lp[2];
#pragma unroll
    for (int et = 0; et < 4; ++et)
#pragma unroll
        for (int qt = 0; qt < 2; ++qt) O[et][qt] = (f32x4)0.0f;
    lp[0] = lp[1] = 0.0f;

    // issue tile 0 into buffer 0
#pragma unroll
    for (int j = 0; j < 4; ++j) {
        async16(&kg[(size_t)krow[j] * Eh + kcol[j] * 8],
                &kst[0][(wid * 256 + j * 64) * 8]);
        async16(&vg[(size_t)vrow[j] * Sq + vcol[j] * 8],
                &vst[0][(wid * 256 + j * 64) * 8]);
    }

    for (int kt = 0; kt < Sq / 128; ++kt) {
        const int cur = kt & 1;
        __syncthreads();   // drains tile kt's async loads; frees other buffer

        if (kt < Sq / 128 - 1) {
            const int t1 = (kt + 1) * 128;
#pragma unroll
            for (int j = 0; j < 4; ++j) {
                async16(&kg[(size_t)(t1 + krow[j]) * Eh + kcol[j] * 8],
                        &kst[cur ^ 1][(wid * 256 + j * 64) * 8]);
                async16(&vg[(size_t)vrow[j] * Sq + t1 + vcol[j] * 8],
                        &vst[cur ^ 1][(wid * 256 + j * 64) * 8]);
            }
        }

        const u16* kcur = kst[cur];
        const u16* vcur = vst[cur];

        // ---- S^T = K' Q^T in two tt-halves; exp/pack interleaves ----
        bf16x4 pf[8][2];   // [ttg][qt]: PV B-frags, k=quad*4+j == C reg r
#pragma unroll
        for (int half = 0; half < 2; ++half) {
            f32x4 S[4][2];
#pragma unroll
            for (int tt = 0; tt < 4; ++tt)
#pragma unroll
                for (int qt = 0; qt < 2; ++qt) S[tt][qt] = (f32x4)0.0f;
#pragma unroll
            for (int ks = 0; ks < 2; ++ks)
#pragma unroll
                for (int tt = 0; tt < 4; ++tt) {
                    int t = (half * 4 + tt) * 16 + l15;
                    bf16x8 kf = *(const bf16x8*)&kcur[t * 64 + ((ks * 4 + quad) ^ (t & 7)) * 8];
                    S[tt][0] = __builtin_amdgcn_mfma_f32_16x16x32_bf16(kf, qf[0][ks], S[tt][0], 0, 0, 0);
                    S[tt][1] = __builtin_amdgcn_mfma_f32_16x16x32_bf16(kf, qf[1][ks], S[tt][1], 0, 0, 0);
                }
#pragma unroll
            for (int tt = 0; tt < 4; ++tt)
#pragma unroll
                for (int qt = 0; qt < 2; ++qt)
#pragma unroll
                    for (int r = 0; r < 4; ++r) {
                        float p = fast_exp2(S[tt][qt][r]);
                        lp[qt] += p;
                        pf[half * 4 + tt][qt][r] = (short)(__float_as_uint(p) >> 16);
                    }
        }

        // ---- O^T += V^T P^T  (16x16x16, A = V^T b64 frags) ----
#pragma unroll
        for (int et = 0; et < 4; ++et) {
            int e = et * 16 + l15;
#pragma unroll
            for (int ttg = 0; ttg < 8; ++ttg) {
                int c  = ttg * 2 + (quad >> 1);
                int gc = (c & 8) | ((c & 7) ^ (e & 7));
                bf16x4 vf = *(const bf16x4*)&vcur[e * 128 + gc * 8 + (quad & 1) * 4];
                O[et][0] = mfma_16x16x16(vf, pf[ttg][0], O[et][0]);
                O[et][1] = mfma_16x16x16(vf, pf[ttg][1], O[et][1]);
            }
        }
    }

    // ---- l: sum the 4 quad-residues (t mod 16 groups) per q ----
#pragma unroll
    for (int qt = 0; qt < 2; ++qt) {
        float v = lp[qt];
        v += __shfl_xor(v, 16, 64);
        v += __shfl_xor(v, 32, 64);
        lp[qt] = v;
    }

    // ---- normalize (per-lane q!) and store u16x4 along e ----
#pragma unroll
    for (int qt = 0; qt < 2; ++qt) {
        const int qglob = q0 + wid * 32 + qt * 16 + l15;
        const float rl = 1.0f / lp[qt];
        u16* crow = ctxb + ((size_t)(b * Sq + qglob) * Hn + h) * Eh;
#pragma unroll
        for (int et = 0; et < 4; ++et) {
            u16x4 o;
#pragma unroll
            for (int r = 0; r < 4; ++r) o[r] = f2bf(O[et][qt][r] * rl);
            *(u16x4*)&crow[et * 16 + quad * 4] = o;
        }
    }
}

// ---------------------------------------------------------------------------
// Flat GEMM [8192,512] x WT[512,512], tile 128x64 (512 blocks, 2/CU).
// MODE 0: bf16 out; 1: bf16 out + relu; 2: fp32 out.
// ---------------------------------------------------------------------------
template<int MODE>
__global__ __launch_bounds__(256, 2) void gemmMN(
    const u16* __restrict__ A, const u16* __restrict__ WT,
    const float* __restrict__ bias, void* __restrict__ Cout)
{
    __shared__ __align__(16) u16 Ast[128 * 64];
    __shared__ __align__(16) u16 Bst[64 * 64];

    f32x4 acc[4][2];
#pragma unroll
    for (int i = 0; i < 4; ++i)
#pragma unroll
        for (int j = 0; j < 2; ++j) acc[i][j] = (f32x4)0.0f;

    gemm_core<64, 2>(A, WT, blockIdx.x * 128, blockIdx.y * 64, Ast, Bst, acc);

    const int tid = threadIdx.x;
    const int lane = tid & 63, wid = tid >> 6;
    const int l15 = lane & 15, quad = lane >> 4;
    const int m0 = blockIdx.x * 128 + (wid >> 1) * 64;
    const int n0 = blockIdx.y * 64 + (wid & 1) * 32;

#pragma unroll
    for (int mt = 0; mt < 4; ++mt)
#pragma unroll
        for (int nt = 0; nt < 2; ++nt) {
            int col = n0 + nt * 16 + l15;
            float bval = bias[col];
#pragma unroll
            for (int r = 0; r < 4; ++r) {
                int row = m0 + mt * 16 + quad * 4 + r;
                float v = acc[mt][nt][r] + bval;
                if (MODE == 1) v = fmaxf(v, 0.0f);
                if (MODE == 2) ((float*)Cout)[(size_t)row * Dm + col] = v;
                else           ((u16*)Cout)[(size_t)row * Dm + col] = f2bf(v);
            }
        }
}

extern "C" void kernel_launch(void* const* d_in, const int* in_sizes, int n_in,
                              void* d_out, int out_size, void* d_ws, size_t ws_size,
                              hipStream_t stream)
{
    const float* x  = (const float*)d_in[0];
    const float* wq = (const float*)d_in[1];
    const float* bq = (const float*)d_in[2];
    const float* wk = (const float*)d_in[3];
    const float* bk = (const float*)d_in[4];
    const float* wv = (const float*)d_in[5];
    const float* bv = (const float*)d_in[6];
    const float* wo = (const float*)d_in[7];
    const float* bo = (const float*)d_in[8];
    const float* w1 = (const float*)d_in[9];
    const float* b1 = (const float*)d_in[10];
    const float* w2 = (const float*)d_in[11];
    const float* b2 = (const float*)d_in[12];
    float* out = (float*)d_out;
    char* wsb = (char*)d_ws;

    const size_t MB = 1u << 20;
    u16*   xb    = (u16*)(wsb + 0);        // 8 MB  bf16 [B*S, D]
    u16*   qb    = (u16*)(wsb + 8 * MB);   // 8 MB  [bh][s][e]
    u16*   kb    = (u16*)(wsb + 16 * MB);  // 8 MB  [bh][s][e] (pre-scaled)
    u16*   vbT   = (u16*)(wsb + 24 * MB);  // 8 MB  [bh][e][s]
    u16*   ctxb  = (u16*)(wsb + 32 * MB);  // 8 MB  [b][s][h][e]
    u16*   ybuf  = (u16*)(wsb + 40 * MB);  // 8 MB
    u16*   h1    = (u16*)(wsb + 48 * MB);  // 8 MB
    u16*   wqkvT = (u16*)(wsb + 56 * MB);  // 1.5 MB
    u16*   woT   = (u16*)(wsb + 58 * MB);  // 0.5 MB
    u16*   w1T   = (u16*)(wsb + 59 * MB);  // 0.5 MB
    u16*   w2T   = (u16*)(wsb + 60 * MB);  // 0.5 MB
    float* bo_s  = (float*)(wsb + 61 * MB);

    prep_kernel<<<dim3(64, 8), 256, 0, stream>>>(
        x, wq, wk, wv, wo, w1, w2, bo, xb, wqkvT, woT, w1T, w2T, bo_s);
    qkv_gemm<<<dim3(Sq * Bsz / 128, 24), 256, 0, stream>>>(
        xb, wqkvT, bq, bk, bv, qb, kb, vbT);
    attn_kernel<<<dim3(Sq / 128, Bsz * Hn), 256, 0, stream>>>(qb, kb, vbT, ctxb);
    gemmMN<0><<<dim3(Bsz * Sq / 128, Dm / 64), 256, 0, stream>>>(ctxb, woT, bo_s, ybuf);
    gemmMN<1><<<dim3(Bsz * Sq / 128, Dm / 64), 256, 0, stream>>>(ybuf, w1T, b1, h1);
    gemmMN<2><<<dim3(Bsz * Sq / 128, Dm / 64), 256, 0, stream>>>(h1, w2T, b2, out);
}